// Round 9
// baseline (5821.090 us; speedup 1.0000x reference)
//
#include <hip/hip_runtime.h>
#include <math.h>

#define BATCH 512
#define LOG2PI 1.8378770664093453f

typedef __attribute__((ext_vector_type(8))) short bfrag;   // 8 bf16
typedef __attribute__((ext_vector_type(4))) float f32x4;
typedef __attribute__((ext_vector_type(4))) unsigned int u32x4;

#define MFMA(a,b,c) __builtin_amdgcn_mfma_f32_16x16x32_bf16(a,b,c,0,0,0)
#define ASTORE(p,v) __hip_atomic_store((p),(v),__ATOMIC_RELAXED,__HIP_MEMORY_SCOPE_AGENT)
#define ALOAD(p)    __hip_atomic_load((p),__ATOMIC_RELAXED,__HIP_MEMORY_SCOPE_AGENT)

// 16B device-coherent store (sc1): data lands at L3, visible cross-XCD after
// vmcnt drain (proven rounds 6-8).
__device__ __forceinline__ void st16_sc1(void* p, u32x4 v){
  asm volatile("global_store_dwordx4 %0, %1, off sc1" :: "v"(p), "v"(v) : "memory");
}
// 16B coherent load: volatile -> sc0 sc1 (bypass L1/L2, read L3 point of
// coherence). Replaces the per-phase acquire fence.
__device__ __forceinline__ bfrag vld16(const unsigned short* p){
  u32x4 v = *(const volatile u32x4*)p;
  union { u32x4 u; bfrag b; } c; c.u = v; return c.b;
}

__device__ __forceinline__ float sigm(float x){ return 1.0f/(1.0f+__expf(-x)); }
__device__ __forceinline__ unsigned short f2bf(float f){
  unsigned int u = __builtin_bit_cast(unsigned int, f);
  u += 0x7FFFu + ((u>>16)&1u);          // RNE
  return (unsigned short)(u>>16);
}
__device__ __forceinline__ bfrag cvt8(const float* __restrict__ p){
  bfrag v;
  #pragma unroll
  for (int e=0;e<8;++e) v[e] = (short)f2bf(p[e]);
  return v;
}
__device__ __forceinline__ bfrag cvt8d(const float* __restrict__ p1, const float* __restrict__ p0){
  bfrag v;
  #pragma unroll
  for (int e=0;e<8;++e) v[e] = (short)f2bf(p1[e]-p0[e]);
  return v;
}

struct Params {
  const float *states, *zin;
  const float *Wih0, *Whh0, *bih0, *bhh0;
  const float *Wih1, *Whh1, *bih1, *bhh1;
  const float *Wfc1, *bfc1, *Wfc2, *bfc2;
  const float *Wmean, *bmean, *Wlv, *blv;
  unsigned short *h0x0, *h0x1, *h0x2;      // h0 triple buffer
  unsigned short *h1x0, *h1x1, *h1x2;      // h1 triple buffer
  unsigned short *d1x0, *d1x1, *d1x2;      // dh1 triple buffer
  unsigned short *d2x0, *d2x1, *d2x2;      // dh2 triple buffer
  float *out;
};

// XCD-aware roles (xg = blk&7, sub = blk>>3); dataflow flags as round 8.
__global__ __launch_bounds__(256, 1) void fused(Params P, unsigned* flags) {
  __shared__ unsigned short sm[74752];   // 149504 B static LDS
  const int tid  = threadIdx.x;
  const int lane = tid & 63;
  const int wv   = tid >> 6;
  const int r16  = lane & 15, kg = lane >> 4;
  const int blk  = blockIdx.x;
  const int xg   = blk & 7, sub = blk >> 3;

  unsigned short* h0b[3]  = {P.h0x0, P.h0x1, P.h0x2};
  unsigned short* h1b[3]  = {P.h1x0, P.h1x1, P.h1x2};
  unsigned short* dh1b[3] = {P.d1x0, P.d1x1, P.d1x2};
  unsigned short* dh2b[3] = {P.d2x0, P.d2x1, P.d2x2};

  // ---------------- startup: stage weights (+z) into LDS (bf16) -----------
  if (xg < 4) {
    const int jt = sub;
    const float* Wsrc[2] = {P.Wih1, P.Whh1};
    #pragma unroll
    for (int m = 0; m < 2; ++m) {
      const float* W = Wsrc[m];
      for (int c = tid; c < 3072; c += 256) {
        int g = c >> 10, rem = c & 1023;
        int r = rem >> 6, k = (rem & 63) << 3;
        *(bfrag*)&sm[(g*16+r)*1032 + m*512 + k] =
          cvt8(&W[((size_t)(g*512 + jt*16 + r))*512 + k]);
      }
    }
  } else if (xg < 6) {
    const int jt = sub;
    for (int c = tid; c < 384; c += 256) {
      int g = c >> 7, rem = c & 127;
      int r = rem >> 3, k = (rem & 7) << 3;
      *(bfrag*)&sm[(g*16+r)*584 + k] =
        cvt8(&P.Wih0[((size_t)(g*512 + jt*16 + r))*64 + k]);
    }
    for (int c = tid; c < 3072; c += 256) {
      int g = c >> 10, rem = c & 1023;
      int r = rem >> 6, k = (rem & 63) << 3;
      *(bfrag*)&sm[(g*16+r)*584 + 64 + k] =
        cvt8(&P.Whh0[((size_t)(g*512 + jt*16 + r))*512 + k]);
    }
  } else if (xg == 6) {
    const int bn = (sub & 7) * 64;
    const int bmB = (sub >> 3) * 128;
    for (int c = tid; c < 4864; c += 256) {
      int n = c / 76, k = (c % 76) << 3;
      *(bfrag*)&sm[n*616 + k] = cvt8(&P.Wfc1[(size_t)(bn + n)*608 + k]);
    }
    for (int c = tid; c < 1024; c += 256) {      // z slice rows bmB..bmB+127
      int r = c >> 3, k = (c & 7) << 3;
      *(bfrag*)&sm[47616 + r*64 + k] = cvt8(&P.zin[(size_t)(bmB + r)*64 + k]);
    }
  } else {
    const int bn = (sub & 7) * 64;
    for (int c = tid; c < 4096; c += 256) {
      int n = c >> 6, k = (c & 63) << 3;
      *(bfrag*)&sm[n*520 + k] = cvt8(&P.Wfc2[(size_t)(bn + n)*512 + k]);
    }
    for (int c = tid; c < 4096; c += 256) {
      int m = c >> 6, k = (c & 63) << 3;
      const float* src = (m < 32) ? &P.Wmean[(size_t)m*512 + k]
                                  : &P.Wlv[(size_t)(m-32)*512 + k];
      *(bfrag*)&sm[33280 + m*520 + k] = cvt8(src);
    }
  }

  // ---------------- hoisted per-thread biases ----------------
  float b0 = 0.f, b1 = 0.f, b2 = 0.f, b3 = 0.f;
  if (xg < 4) {
    int j = sub*16 + r16;
    b0 = P.bih1[j] + P.bhh1[j];
    b1 = P.bih1[j+512] + P.bhh1[j+512];
    b2 = P.bih1[j+1024]; b3 = P.bhh1[j+1024];
  } else if (xg < 6) {
    int j = sub*16 + r16;
    b0 = P.bih0[j] + P.bhh0[j];
    b1 = P.bih0[j+512] + P.bhh0[j+512];
    b2 = P.bih0[j+1024]; b3 = P.bhh0[j+1024];
  } else if (xg == 6) {
    int nn0 = (sub & 7)*64 + (wv&1)*32 + r16;
    b0 = P.bfc1[nn0]; b1 = P.bfc1[nn0+16];
  } else {
    int nn0 = (sub & 7)*64 + (wv&1)*32 + r16;
    b0 = P.bfc2[nn0]; b1 = P.bfc2[nn0+16];
    int c = wv*16 + r16;
    b2 = (c < 32) ? P.bmean[c] : P.blv[c-32];
  }
  float hs[4][4] = {};                  // gru f32 master state (regs)
  float nacc0 = 0.f, nacc1 = 0.f;

  for (int u = 0; u <= 256; ++u) {
    // -------------------- dataflow wait (round-8 sets) --------------------
    if (wv == 0) {
      int pb1 = -1, pb2 = -1;
      const unsigned t1 = (unsigned)u, t2 = (unsigned)(u - 1);
      if (xg >= 4 && xg < 6) {
        if (u >= 1 && lane < 32) pb1 = lane*8 + xg;
        if (u >= 2)              pb2 = (lane>>1)*8 + 2*(xg-4) + (lane&1);
      } else if (xg < 4) {
        if (u >= 1) pb1 = (lane < 32) ? lane*8 + xg : (lane-32)*8 + 4 + (xg>>1);
        if (u >= 2 && lane < 8) pb2 = (xg*8 + lane)*8 + 6;
      } else if (xg == 6) {
        if (u >= 1 && lane < 32) pb1 = lane*8 + (sub>>3);
        if (u >= 2 && lane < 8)  pb2 = ((sub & ~7) + lane)*8 + 7;
      } else {
        if (u >= 1 && lane < 16) pb1 = ((sub & ~7) + (lane&7))*8 + ((lane<8)?6:7);
      }
      unsigned spin = 0;
      while (true) {
        bool ok = true;
        if (pb1 >= 0) ok &= (ALOAD(&flags[pb1*16]) >= t1);
        if (pb2 >= 0) ok &= (ALOAD(&flags[pb2*16]) >= t2);
        if (__all(ok)) break;
        if (++spin > (1u<<26)) break;   // safety: never hang the harness
        __builtin_amdgcn_s_sleep(1);
      }
    }
    __syncthreads();                    // no fence: reads are sc0sc1-coherent

    const int iu   = u % 3;             // (u-3)%3 == u%3
    const int ium1 = (u+2) % 3;         // (u-1)%3
    const int ium2 = (u+1) % 3;         // (u-2)%3

    if (xg < 4) {
      // ---------------- gru1, step t = u-1 ----------------
      if (u >= 1 && u <= 254) {
        const int jt = sub, bmB = xg * 128;
        const unsigned short* h0r = h0b[ium1];      // h0(t)
        const unsigned short* h1r = h1b[ium2];      // h1(t-1)
        f32x4 R[2]={}, Z[2]={}, NI[2]={}, NH[2]={};
        const int row0 = bmB + wv*32 + r16;
        const unsigned short* pA = h0r + (size_t)row0*512 + kg*8;
        const unsigned short* pB = pA + 16*512;
        const unsigned short* qA = h1r + (size_t)row0*512 + kg*8;
        const unsigned short* qB = qA + 16*512;
        bfrag s0[8], s1[8];
        #pragma unroll
        for (int p = 0; p < 8; ++p) { s0[p]=vld16(pA+p*32); s1[p]=vld16(pB+p*32); }
        #pragma unroll
        for (int q = 0; q < 32; ++q) {
          const int slot = q & 7;
          bfrag a0 = s0[slot], a1 = s1[slot];
          if (q + 8 < 32) {
            const int n = q + 8;
            if (n < 16) { s0[slot]=vld16(pA+n*32);      s1[slot]=vld16(pB+n*32); }
            else        { s0[slot]=vld16(qA+(n-16)*32); s1[slot]=vld16(qB+(n-16)*32); }
          }
          const int kl = (q < 16 ? q*32 : 512 + (q-16)*32) + kg*8;
          bfrag bR = *(const bfrag*)&sm[(0*16+r16)*1032 + kl];
          bfrag bZ = *(const bfrag*)&sm[(1*16+r16)*1032 + kl];
          bfrag bN = *(const bfrag*)&sm[(2*16+r16)*1032 + kl];
          R[0]=MFMA(a0,bR,R[0]); R[1]=MFMA(a1,bR,R[1]);
          Z[0]=MFMA(a0,bZ,Z[0]); Z[1]=MFMA(a1,bZ,Z[1]);
          if (q < 16) { NI[0]=MFMA(a0,bN,NI[0]); NI[1]=MFMA(a1,bN,NI[1]); }
          else        { NH[0]=MFMA(a0,bN,NH[0]); NH[1]=MFMA(a1,bN,NH[1]); }
        }
        unsigned short* exch = sm + 49536;          // [128][16]
        #pragma unroll
        for (int fm = 0; fm < 2; ++fm)
          #pragma unroll
          for (int e = 0; e < 4; ++e) {
            int rl = wv*32 + fm*16 + kg*4 + e;
            float r  = sigm(R[fm][e] + b0);
            float zg = sigm(Z[fm][e] + b1);
            float nn = tanhf(NI[fm][e] + b2 + r*(NH[fm][e] + b3));
            float hn = (1.f - zg)*nn + zg*hs[fm][e];
            hs[fm][e] = hn;
            exch[rl*16 + r16] = f2bf(hn);
          }
        __syncthreads();
        {
          unsigned short* dst = h1b[ium1];          // h1(t) = step u-1
          int r = tid >> 1, hc = tid & 1;
          u32x4 v = *(const u32x4*)&exch[r*16 + hc*8];
          st16_sc1(dst + ((size_t)(bmB + r))*512 + jt*16 + hc*8, v);
        }
      }
    } else if (xg < 6) {
      // ---------------- gru0, step t = u ----------------
      if (u <= 253) {
        const int jt = sub, bmB = (xg - 4) * 256;
        const unsigned short* h0r = h0b[ium1];      // h0(t-1)
        const float* s0p = P.states + (size_t)u*BATCH*32;
        f32x4 R[4]={}, Z[4]={}, NI[4]={}, NH[4]={};
        bfrag st[4][4];                             // [slot][fm] prefetch
        #pragma unroll
        for (int p = 0; p < 4; ++p)
          #pragma unroll
          for (int fm = 0; fm < 4; ++fm)
            st[p][fm] = vld16(h0r + (size_t)(bmB + wv*64 + fm*16 + r16)*512 + p*32 + kg*8);
        #pragma unroll
        for (int ks = 0; ks < 2; ++ks) {             // K=64: s then a (plain cached)
          const int kl = ks*32 + kg*8;
          bfrag a[4];
          #pragma unroll
          for (int fm = 0; fm < 4; ++fm) {
            int row = bmB + wv*64 + fm*16 + r16;
            a[fm] = (ks == 0)
              ? cvt8(&s0p[(size_t)row*32 + kg*8])
              : cvt8d(&s0p[(size_t)(BATCH + row)*32 + kg*8], &s0p[(size_t)row*32 + kg*8]);
          }
          bfrag bR = *(const bfrag*)&sm[(0*16+r16)*584 + kl];
          bfrag bZ = *(const bfrag*)&sm[(1*16+r16)*584 + kl];
          bfrag bN = *(const bfrag*)&sm[(2*16+r16)*584 + kl];
          #pragma unroll
          for (int fm = 0; fm < 4; ++fm) {
            R[fm]=MFMA(a[fm],bR,R[fm]); Z[fm]=MFMA(a[fm],bZ,Z[fm]); NI[fm]=MFMA(a[fm],bN,NI[fm]);
          }
        }
        #pragma unroll
        for (int kt = 0; kt < 16; ++kt) {            // K=512: h0, pipelined
          const int slot = kt & 3;
          bfrag a[4];
          #pragma unroll
          for (int fm = 0; fm < 4; ++fm) {
            a[fm] = st[slot][fm];
            if (kt + 4 < 16)
              st[slot][fm] = vld16(h0r + (size_t)(bmB + wv*64 + fm*16 + r16)*512 + (kt+4)*32 + kg*8);
          }
          const int kl = 64 + kt*32 + kg*8;
          bfrag bR = *(const bfrag*)&sm[(0*16+r16)*584 + kl];
          bfrag bZ = *(const bfrag*)&sm[(1*16+r16)*584 + kl];
          bfrag bN = *(const bfrag*)&sm[(2*16+r16)*584 + kl];
          #pragma unroll
          for (int fm = 0; fm < 4; ++fm) {
            R[fm]=MFMA(a[fm],bR,R[fm]); Z[fm]=MFMA(a[fm],bZ,Z[fm]); NH[fm]=MFMA(a[fm],bN,NH[fm]);
          }
        }
        unsigned short* exch = sm + 28032;          // [256][16]
        #pragma unroll
        for (int fm = 0; fm < 4; ++fm)
          #pragma unroll
          for (int e = 0; e < 4; ++e) {
            int rl = wv*64 + fm*16 + kg*4 + e;
            float r  = sigm(R[fm][e] + b0);
            float zg = sigm(Z[fm][e] + b1);
            float nn = tanhf(NI[fm][e] + b2 + r*(NH[fm][e] + b3));
            float hn = (1.f - zg)*nn + zg*hs[fm][e];
            hs[fm][e] = hn;
            exch[rl*16 + r16] = f2bf(hn);
          }
        __syncthreads();
        {
          unsigned short* dst = h0b[iu];            // h0(t) = step u
          int r = tid;
          u32x4 v0 = *(const u32x4*)&exch[r*16];
          u32x4 v1 = *(const u32x4*)&exch[r*16 + 8];
          unsigned short* dp = dst + ((size_t)(bmB + r))*512 + jt*16;
          st16_sc1(dp,     v0);
          st16_sc1(dp + 8, v1);
        }
      }
    } else if (xg == 6) {
      // ---------------- fc1, step t = u-1 ----------------
      if (u >= 1 && u <= 254) {
        const int bmB = (sub >> 3) * 128, bnB = (sub & 7) * 64;
        const unsigned short* h1r = h1b[ium2];      // h1(t-1)
        const float* s0p = P.states + (size_t)(u-1)*BATCH*32;
        f32x4 acc[4][2] = {};
        const int arow = bmB + (wv>>1)*64;
        const int bcol = (wv&1)*32;
        bfrag st[4][4];                             // prefetch h1 c_kt 0..3
        #pragma unroll
        for (int p = 0; p < 4; ++p)
          #pragma unroll
          for (int fm = 0; fm < 4; ++fm)
            st[p][fm] = vld16(h1r + (size_t)(arow + fm*16 + r16)*512 + p*32 + kg*8);
        #pragma unroll
        for (int kt = 0; kt < 3; ++kt) {            // k<96: states + z(LDS)
          const int k = kt*32 + kg*8;
          bfrag a[4];
          #pragma unroll
          for (int fm = 0; fm < 4; ++fm) {
            int row = arow + fm*16 + r16;
            int rl  = row - bmB;
            if (kt == 0) a[fm] = cvt8(&s0p[(size_t)row*32 + k]);
            else         a[fm] = *(const bfrag*)&sm[47616 + rl*64 + (k - 32)];
          }
          bfrag bf0 = *(const bfrag*)&sm[(bcol      + r16)*616 + k];
          bfrag bf1 = *(const bfrag*)&sm[(bcol + 16 + r16)*616 + k];
          #pragma unroll
          for (int fm = 0; fm < 4; ++fm) {
            acc[fm][0] = MFMA(a[fm], bf0, acc[fm][0]);
            acc[fm][1] = MFMA(a[fm], bf1, acc[fm][1]);
          }
        }
        #pragma unroll
        for (int ck = 0; ck < 16; ++ck) {           // k>=96: h1, pipelined
          const int slot = ck & 3;
          bfrag a[4];
          #pragma unroll
          for (int fm = 0; fm < 4; ++fm) {
            a[fm] = st[slot][fm];
            if (ck + 4 < 16)
              st[slot][fm] = vld16(h1r + (size_t)(arow + fm*16 + r16)*512 + (ck+4)*32 + kg*8);
          }
          const int k = 96 + ck*32 + kg*8;
          bfrag bf0 = *(const bfrag*)&sm[(bcol      + r16)*616 + k];
          bfrag bf1 = *(const bfrag*)&sm[(bcol + 16 + r16)*616 + k];
          #pragma unroll
          for (int fm = 0; fm < 4; ++fm) {
            acc[fm][0] = MFMA(a[fm], bf0, acc[fm][0]);
            acc[fm][1] = MFMA(a[fm], bf1, acc[fm][1]);
          }
        }
        unsigned short* exch = sm + 39424;          // [128][64]
        #pragma unroll
        for (int fm = 0; fm < 4; ++fm)
          #pragma unroll
          for (int fn = 0; fn < 2; ++fn) {
            float bias = fn ? b1 : b0;
            #pragma unroll
            for (int e = 0; e < 4; ++e) {
              int rl = (wv>>1)*64 + fm*16 + kg*4 + e;
              int cl = bcol + fn*16 + r16;
              exch[rl*64 + cl] = f2bf(fmaxf(acc[fm][fn][e] + bias, 0.f));
            }
          }
        __syncthreads();
        {
          unsigned short* dst = dh1b[ium1];         // dh1(t) = step u-1
          int r = tid >> 1, hc = tid & 1;
          #pragma unroll
          for (int q = 0; q < 4; ++q) {
            u32x4 v = *(const u32x4*)&exch[r*64 + hc*32 + q*8];
            st16_sc1(dst + ((size_t)(bmB + r))*512 + bnB + hc*32 + q*8, v);
          }
        }
        __syncthreads();
      }
    } else {
      // ---------------- fc2, step t = u-2 ----------------
      if (u >= 2 && u <= 255) {
        const int bmB = (sub >> 3) * 128, bnB = (sub & 7) * 64;
        const unsigned short* dr = dh1b[ium2];      // dh1(t)
        f32x4 acc[4][2] = {};
        const int arow = bmB + (wv>>1)*64;
        const int bcol = (wv&1)*32;
        bfrag st[4][4];
        #pragma unroll
        for (int p = 0; p < 4; ++p)
          #pragma unroll
          for (int fm = 0; fm < 4; ++fm)
            st[p][fm] = vld16(dr + (size_t)(arow + fm*16 + r16)*512 + p*32 + kg*8);
        #pragma unroll
        for (int kt = 0; kt < 16; ++kt) {
          const int slot = kt & 3;
          bfrag a[4];
          #pragma unroll
          for (int fm = 0; fm < 4; ++fm) {
            a[fm] = st[slot][fm];
            if (kt + 4 < 16)
              st[slot][fm] = vld16(dr + (size_t)(arow + fm*16 + r16)*512 + (kt+4)*32 + kg*8);
          }
          const int k = kt*32 + kg*8;
          bfrag bf0 = *(const bfrag*)&sm[(bcol      + r16)*520 + k];
          bfrag bf1 = *(const bfrag*)&sm[(bcol + 16 + r16)*520 + k];
          #pragma unroll
          for (int fm = 0; fm < 4; ++fm) {
            acc[fm][0] = MFMA(a[fm], bf0, acc[fm][0]);
            acc[fm][1] = MFMA(a[fm], bf1, acc[fm][1]);
          }
        }
        unsigned short* exch = sm + 66560;          // [128][64]
        #pragma unroll
        for (int fm = 0; fm < 4; ++fm)
          #pragma unroll
          for (int fn = 0; fn < 2; ++fn) {
            float bias = fn ? b1 : b0;
            #pragma unroll
            for (int e = 0; e < 4; ++e) {
              int rl = (wv>>1)*64 + fm*16 + kg*4 + e;
              int cl = bcol + fn*16 + r16;
              exch[rl*64 + cl] = f2bf(fmaxf(acc[fm][fn][e] + bias, 0.f));
            }
          }
        __syncthreads();
        {
          unsigned short* dst = dh2b[ium2];         // dh2(t) = step u-2
          int r = tid >> 1, hc = tid & 1;
          #pragma unroll
          for (int q = 0; q < 4; ++q) {
            u32x4 v = *(const u32x4*)&exch[r*64 + hc*32 + q*8];
            st16_sc1(dst + ((size_t)(bmB + r))*512 + bnB + hc*32 + q*8, v);
          }
        }
      }
      // ---------------- head, step t = u-3 ----------------
      if (u >= 3) {
        const int t = u - 3;
        const unsigned short* dr = dh2b[iu];        // dh2(u-3)
        f32x4 acc = {};
        const unsigned short* hp = dr + (size_t)(sub*16 + r16)*512 + kg*8;
        bfrag hs8[8];
        #pragma unroll
        for (int p = 0; p < 8; ++p) hs8[p] = vld16(hp + p*32);
        #pragma unroll
        for (int kt = 0; kt < 16; ++kt) {
          const int slot = kt & 7;
          bfrag a = hs8[slot];
          if (kt + 8 < 16) hs8[slot] = vld16(hp + (kt+8)*32);
          bfrag b = *(const bfrag*)&sm[33280 + (wv*16 + r16)*520 + kt*32 + kg*8];
          acc = MFMA(a, b, acc);
        }
        __syncthreads();                    // fc2's exch use is done
        float* exch = (float*)(sm + 66560); // [16][66]
        const int c = wv*16 + r16;
        #pragma unroll
        for (int e = 0; e < 4; ++e)
          exch[(kg*4+e)*66 + c] = acc[e] + b2;
        __syncthreads();
        const float* s0p = P.states + (size_t)t*BATCH*32;
        #pragma unroll
        for (int e2 = 0; e2 < 2; ++e2) {
          int idx = tid*2 + e2;
          int r = idx >> 5, i = idx & 31;
          int b = sub*16 + r;
          float mean = exch[r*66 + i], lv = exch[r*66 + 32 + i];
          float av = s0p[(size_t)(BATCH + b)*32 + i] - s0p[(size_t)b*32 + i];
          float d = av - mean;
          float v = 0.5f*(d*d*__expf(-lv) + lv + LOG2PI);
          if (e2) nacc1 += v; else nacc0 += v;
        }
      }
    }

    // -------------------- publish --------------------
    __syncthreads();                      // drains all threads' sc1 stores
    if (tid == 0) ASTORE(&flags[blk*16], (unsigned)(u+1));
  }

  if (xg == 7) {
    #pragma unroll
    for (int e2 = 0; e2 < 2; ++e2) {
      int idx = tid*2 + e2;
      int b = sub*16 + (idx >> 5), i = idx & 31;
      P.out[(size_t)b*32 + i] = e2 ? nacc1 : nacc0;
    }
  }
}

extern "C" void kernel_launch(void* const* d_in, const int* in_sizes, int n_in,
                              void* d_out, int out_size, void* d_ws, size_t ws_size,
                              hipStream_t stream) {
  Params P;
  P.states = (const float*)d_in[0];
  P.zin    = (const float*)d_in[1];
  P.Wih0   = (const float*)d_in[2];
  P.Whh0   = (const float*)d_in[3];
  P.bih0   = (const float*)d_in[4];
  P.bhh0   = (const float*)d_in[5];
  P.Wih1   = (const float*)d_in[6];
  P.Whh1   = (const float*)d_in[7];
  P.bih1   = (const float*)d_in[8];
  P.bhh1   = (const float*)d_in[9];
  P.Wfc1   = (const float*)d_in[10];
  P.bfc1   = (const float*)d_in[11];
  P.Wfc2   = (const float*)d_in[12];
  P.bfc2   = (const float*)d_in[13];
  P.Wmean  = (const float*)d_in[14];
  P.bmean  = (const float*)d_in[15];
  P.Wlv    = (const float*)d_in[16];
  P.blv    = (const float*)d_in[17];
  P.out = (float*)d_out;

  const size_t HB = (size_t)512*512;
  unsigned short* u = (unsigned short*)d_ws;
  P.h0x0 = u;        P.h0x1 = u + HB;   P.h0x2 = u + 2*HB;
  P.h1x0 = u + 3*HB; P.h1x1 = u + 4*HB; P.h1x2 = u + 5*HB;
  P.d1x0 = u + 6*HB; P.d1x1 = u + 7*HB; P.d1x2 = u + 8*HB;
  P.d2x0 = u + 9*HB; P.d2x1 = u + 10*HB; P.d2x2 = u + 11*HB;
  unsigned* flags = (unsigned*)(u + 12*HB);   // 256 flags @ 64B stride = 16 KB

  hipMemsetAsync(u, 0, 6*HB*sizeof(unsigned short), stream);   // h0/h1 triple
  hipMemsetAsync(flags, 0, 256*16*sizeof(unsigned), stream);
  hipMemsetAsync(d_out, 0, (size_t)out_size*sizeof(float), stream);

  fused<<<dim3(256), dim3(256), 0, stream>>>(P, flags);
}

// Round 11
// 4338.776 us; speedup vs baseline: 1.3416x; 1.3416x over previous
//
#include <hip/hip_runtime.h>
#include <math.h>

#define BATCH 512
#define LOG2PI 1.8378770664093453f
#define HB 262144   // 512*512 shorts

typedef __attribute__((ext_vector_type(8))) short bfrag;   // 8 bf16
typedef __attribute__((ext_vector_type(4))) float f32x4;
typedef __attribute__((ext_vector_type(4))) unsigned int u32x4;

#define MFMA(a,b,c) __builtin_amdgcn_mfma_f32_16x16x32_bf16(a,b,c,0,0,0)
#define ASTORE(p,v) __hip_atomic_store((p),(v),__ATOMIC_RELAXED,__HIP_MEMORY_SCOPE_AGENT)
#define ALOAD(p)    __hip_atomic_load((p),__ATOMIC_RELAXED,__HIP_MEMORY_SCOPE_AGENT)

// 16B device-coherent store (sc1): data lands at L3, visible cross-XCD after
// vmcnt drain (proven rounds 6-8).
__device__ __forceinline__ void st16_sc1(void* p, u32x4 v){
  asm volatile("global_store_dwordx4 %0, %1, off sc1" :: "v"(p), "v"(v) : "memory");
}

__device__ __forceinline__ float sigm(float x){ return 1.0f/(1.0f+__expf(-x)); }
__device__ __forceinline__ unsigned short f2bf(float f){
  unsigned int u = __builtin_bit_cast(unsigned int, f);
  u += 0x7FFFu + ((u>>16)&1u);          // RNE
  return (unsigned short)(u>>16);
}
__device__ __forceinline__ bfrag cvt8(const float* __restrict__ p){
  bfrag v;
  #pragma unroll
  for (int e=0;e<8;++e) v[e] = (short)f2bf(p[e]);
  return v;
}
__device__ __forceinline__ bfrag cvt8d(const float* __restrict__ p1, const float* __restrict__ p0){
  bfrag v;
  #pragma unroll
  for (int e=0;e<8;++e) v[e] = (short)f2bf(p1[e]-p0[e]);
  return v;
}

struct Params {
  const float *states, *zin;
  const float *Wih0, *Whh0, *bih0, *bhh0;
  const float *Wih1, *Whh1, *bih1, *bhh1;
  const float *Wfc1, *bfc1, *Wfc2, *bfc2;
  const float *Wmean, *bmean, *Wlv, *blv;
  unsigned short *act;   // h0[8*HB] | h1[8*HB] | d1[8*HB] | d2[8*HB]
  float *out;
};

// Roles (xg = blk&7, sub = blk>>3), identical to round 8:
//   xg 0-3: gru1  rows xg*128, j-tile=sub.  LDS: W [3][16][1032], exch@49536
//   xg 4-5: gru0  rows (xg-4)*256, j-tile=sub. LDS: W [3][16][584], exch@28032
//   xg 6:   fc1   bm=sub>>3, bn=sub&7. LDS: W [64][616], exch@39424, z@47616
//   xg 7:   fc2+head. LDS: W x2 @0/33280, exch@66560
// 8-deep buffers (step t -> slot t&7): backpressure slack widens to >= u-6,
// taking the 2-hop cycles off the per-iteration critical path.
__global__ __launch_bounds__(256, 1) void fused(Params P, unsigned* flags) {
  __shared__ unsigned short sm[74752];   // 149504 B static LDS
  const int tid  = threadIdx.x;
  const int lane = tid & 63;
  const int wv   = tid >> 6;
  const int r16  = lane & 15, kg = lane >> 4;
  const int blk  = blockIdx.x;
  const int xg   = blk & 7, sub = blk >> 3;

  unsigned short* h0 = P.act;
  unsigned short* h1 = P.act +  8*(size_t)HB;
  unsigned short* d1 = P.act + 16*(size_t)HB;
  unsigned short* d2 = P.act + 24*(size_t)HB;

  // ---------------- startup: stage weights (+z) into LDS (bf16) -----------
  if (xg < 4) {
    const int jt = sub;
    const float* Wsrc[2] = {P.Wih1, P.Whh1};
    #pragma unroll
    for (int m = 0; m < 2; ++m) {
      const float* W = Wsrc[m];
      for (int c = tid; c < 3072; c += 256) {
        int g = c >> 10, rem = c & 1023;
        int r = rem >> 6, k = (rem & 63) << 3;
        *(bfrag*)&sm[(g*16+r)*1032 + m*512 + k] =
          cvt8(&W[((size_t)(g*512 + jt*16 + r))*512 + k]);
      }
    }
  } else if (xg < 6) {
    const int jt = sub;
    for (int c = tid; c < 384; c += 256) {
      int g = c >> 7, rem = c & 127;
      int r = rem >> 3, k = (rem & 7) << 3;
      *(bfrag*)&sm[(g*16+r)*584 + k] =
        cvt8(&P.Wih0[((size_t)(g*512 + jt*16 + r))*64 + k]);
    }
    for (int c = tid; c < 3072; c += 256) {
      int g = c >> 10, rem = c & 1023;
      int r = rem >> 6, k = (rem & 63) << 3;
      *(bfrag*)&sm[(g*16+r)*584 + 64 + k] =
        cvt8(&P.Whh0[((size_t)(g*512 + jt*16 + r))*512 + k]);
    }
  } else if (xg == 6) {
    const int bn = (sub & 7) * 64;
    const int bmB = (sub >> 3) * 128;
    for (int c = tid; c < 4864; c += 256) {
      int n = c / 76, k = (c % 76) << 3;
      *(bfrag*)&sm[n*616 + k] = cvt8(&P.Wfc1[(size_t)(bn + n)*608 + k]);
    }
    for (int c = tid; c < 1024; c += 256) {      // z slice rows bmB..bmB+127
      int r = c >> 3, k = (c & 7) << 3;
      *(bfrag*)&sm[47616 + r*64 + k] = cvt8(&P.zin[(size_t)(bmB + r)*64 + k]);
    }
  } else {
    const int bn = (sub & 7) * 64;
    for (int c = tid; c < 4096; c += 256) {
      int n = c >> 6, k = (c & 63) << 3;
      *(bfrag*)&sm[n*520 + k] = cvt8(&P.Wfc2[(size_t)(bn + n)*512 + k]);
    }
    for (int c = tid; c < 4096; c += 256) {
      int m = c >> 6, k = (c & 63) << 3;
      const float* src = (m < 32) ? &P.Wmean[(size_t)m*512 + k]
                                  : &P.Wlv[(size_t)(m-32)*512 + k];
      *(bfrag*)&sm[33280 + m*520 + k] = cvt8(src);
    }
  }

  // ---------------- hoisted per-thread biases ----------------
  float b0 = 0.f, b1 = 0.f, b2 = 0.f, b3 = 0.f;
  if (xg < 4) {
    int j = sub*16 + r16;
    b0 = P.bih1[j] + P.bhh1[j];
    b1 = P.bih1[j+512] + P.bhh1[j+512];
    b2 = P.bih1[j+1024]; b3 = P.bhh1[j+1024];
  } else if (xg < 6) {
    int j = sub*16 + r16;
    b0 = P.bih0[j] + P.bhh0[j];
    b1 = P.bih0[j+512] + P.bhh0[j+512];
    b2 = P.bih0[j+1024]; b3 = P.bhh0[j+1024];
  } else if (xg == 6) {
    int nn0 = (sub & 7)*64 + (wv&1)*32 + r16;
    b0 = P.bfc1[nn0]; b1 = P.bfc1[nn0+16];
  } else {
    int nn0 = (sub & 7)*64 + (wv&1)*32 + r16;
    b0 = P.bfc2[nn0]; b1 = P.bfc2[nn0+16];
    int c = wv*16 + r16;
    b2 = (c < 32) ? P.bmean[c] : P.blv[c-32];
  }
  float hs[4][4] = {};                  // gru f32 master state (regs)
  float nacc0 = 0.f, nacc1 = 0.f;

  for (int u = 0; u <= 256; ++u) {
    // ---------- dataflow wait (round-8 sets; backpressure slack -6) ----------
    if (wv == 0) {
      int pb1 = -1, pb2 = -1;
      const unsigned t1 = (unsigned)u, t2 = (unsigned)(u - 6);
      if (xg >= 4 && xg < 6) {          // gru0: own>=u ; gru1 consumers >=u-6
        if (u >= 1 && lane < 32) pb1 = lane*8 + xg;
        if (u >= 7)              pb2 = (lane>>1)*8 + 2*(xg-4) + (lane&1);
      } else if (xg < 4) {              // gru1: own+gru0 >=u ; fc1 >=u-6
        if (u >= 1) pb1 = (lane < 32) ? lane*8 + xg : (lane-32)*8 + 4 + (xg>>1);
        if (u >= 7 && lane < 8) pb2 = (xg*8 + lane)*8 + 6;
      } else if (xg == 6) {             // fc1: gru1 >=u ; fc2 >=u-6
        if (u >= 1 && lane < 32) pb1 = lane*8 + (sub>>3);
        if (u >= 7 && lane < 8)  pb2 = ((sub & ~7) + lane)*8 + 7;
      } else {                          // fc2/head: fc1 + own-group >=u
        if (u >= 1 && lane < 16) pb1 = ((sub & ~7) + (lane&7))*8 + ((lane<8)?6:7);
      }
      unsigned spin = 0;
      while (true) {
        bool ok = true;
        if (pb1 >= 0) ok &= (ALOAD(&flags[pb1*16]) >= t1);
        if (pb2 >= 0) ok &= (ALOAD(&flags[pb2*16]) >= t2);
        if (__all(ok)) break;
        if (++spin > (1u<<26)) break;   // safety: never hang the harness
        __builtin_amdgcn_s_sleep(1);
      }
    }
    __syncthreads();
    if (tid < 64) __builtin_amdgcn_fence(__ATOMIC_ACQUIRE, "agent");
    __syncthreads();

    const int ju  = u & 7;              // slot of step u
    const int jm1 = (u+7) & 7;          // step u-1
    const int jm2 = (u+6) & 7;          // step u-2
    const int jm3 = (u+5) & 7;          // step u-3

    if (xg < 4) {
      // ---------------- gru1, step t = u-1 ----------------
      if (u >= 1 && u <= 254) {
        const int jt = sub, bmB = xg * 128;
        const unsigned short* h0r = h0 + (size_t)jm1*HB;   // h0(t)
        const unsigned short* h1r = h1 + (size_t)jm2*HB;   // h1(t-1)
        f32x4 R[2]={}, Z[2]={}, NI[2]={}, NH[2]={};
        const int row0 = bmB + wv*32 + r16;
        #pragma unroll
        for (int half = 0; half < 2; ++half) {
          const unsigned short* asrc = half ? h1r : h0r;
          #pragma unroll 4
          for (int kt = 0; kt < 16; ++kt) {
            const int kk = kt*32 + kg*8;
            const int kl = half*512 + kk;
            bfrag a0 = *(const bfrag*)&asrc[(size_t)row0*512 + kk];
            bfrag a1 = *(const bfrag*)&asrc[(size_t)(row0+16)*512 + kk];
            bfrag bR = *(const bfrag*)&sm[(0*16+r16)*1032 + kl];
            bfrag bZ = *(const bfrag*)&sm[(1*16+r16)*1032 + kl];
            bfrag bN = *(const bfrag*)&sm[(2*16+r16)*1032 + kl];
            R[0]=MFMA(a0,bR,R[0]); R[1]=MFMA(a1,bR,R[1]);
            Z[0]=MFMA(a0,bZ,Z[0]); Z[1]=MFMA(a1,bZ,Z[1]);
            if (!half) { NI[0]=MFMA(a0,bN,NI[0]); NI[1]=MFMA(a1,bN,NI[1]); }
            else       { NH[0]=MFMA(a0,bN,NH[0]); NH[1]=MFMA(a1,bN,NH[1]); }
          }
        }
        unsigned short* exch = sm + 49536;          // [128][16]
        #pragma unroll
        for (int fm = 0; fm < 2; ++fm)
          #pragma unroll
          for (int e = 0; e < 4; ++e) {
            int rl = wv*32 + fm*16 + kg*4 + e;
            float r  = sigm(R[fm][e] + b0);
            float zg = sigm(Z[fm][e] + b1);
            float nn = tanhf(NI[fm][e] + b2 + r*(NH[fm][e] + b3));
            float hn = (1.f - zg)*nn + zg*hs[fm][e];
            hs[fm][e] = hn;
            exch[rl*16 + r16] = f2bf(hn);
          }
        __syncthreads();
        {
          unsigned short* dst = h1 + (size_t)jm1*HB;       // h1(t) = step u-1
          int r = tid >> 1, hc = tid & 1;
          u32x4 v = *(const u32x4*)&exch[r*16 + hc*8];
          st16_sc1(dst + ((size_t)(bmB + r))*512 + jt*16 + hc*8, v);
        }
      }
    } else if (xg < 6) {
      // ---------------- gru0, step t = u ----------------
      if (u <= 253) {
        const int jt = sub, bmB = (xg - 4) * 256;
        const unsigned short* h0r = h0 + (size_t)jm1*HB;   // h0(t-1)
        const float* s0p = P.states + (size_t)u*BATCH*32;
        f32x4 R[4]={}, Z[4]={}, NI[4]={}, NH[4]={};
        #pragma unroll
        for (int ks = 0; ks < 2; ++ks) {             // K=64: s then a
          const int kl = ks*32 + kg*8;
          bfrag a[4];
          #pragma unroll
          for (int fm = 0; fm < 4; ++fm) {
            int row = bmB + wv*64 + fm*16 + r16;
            a[fm] = (ks == 0)
              ? cvt8(&s0p[(size_t)row*32 + kg*8])
              : cvt8d(&s0p[(size_t)(BATCH + row)*32 + kg*8], &s0p[(size_t)row*32 + kg*8]);
          }
          bfrag bR = *(const bfrag*)&sm[(0*16+r16)*584 + kl];
          bfrag bZ = *(const bfrag*)&sm[(1*16+r16)*584 + kl];
          bfrag bN = *(const bfrag*)&sm[(2*16+r16)*584 + kl];
          #pragma unroll
          for (int fm = 0; fm < 4; ++fm) {
            R[fm]=MFMA(a[fm],bR,R[fm]); Z[fm]=MFMA(a[fm],bZ,Z[fm]); NI[fm]=MFMA(a[fm],bN,NI[fm]);
          }
        }
        #pragma unroll 2
        for (int kt = 0; kt < 16; ++kt) {            // K=512: h0
          const int kk = kt*32 + kg*8;
          const int kl = 64 + kk;
          bfrag a[4];
          #pragma unroll
          for (int fm = 0; fm < 4; ++fm) {
            int row = bmB + wv*64 + fm*16 + r16;
            a[fm] = *(const bfrag*)&h0r[(size_t)row*512 + kk];
          }
          bfrag bR = *(const bfrag*)&sm[(0*16+r16)*584 + kl];
          bfrag bZ = *(const bfrag*)&sm[(1*16+r16)*584 + kl];
          bfrag bN = *(const bfrag*)&sm[(2*16+r16)*584 + kl];
          #pragma unroll
          for (int fm = 0; fm < 4; ++fm) {
            R[fm]=MFMA(a[fm],bR,R[fm]); Z[fm]=MFMA(a[fm],bZ,Z[fm]); NH[fm]=MFMA(a[fm],bN,NH[fm]);
          }
        }
        unsigned short* exch = sm + 28032;          // [256][16]
        #pragma unroll
        for (int fm = 0; fm < 4; ++fm)
          #pragma unroll
          for (int e = 0; e < 4; ++e) {
            int rl = wv*64 + fm*16 + kg*4 + e;
            float r  = sigm(R[fm][e] + b0);
            float zg = sigm(Z[fm][e] + b1);
            float nn = tanhf(NI[fm][e] + b2 + r*(NH[fm][e] + b3));
            float hn = (1.f - zg)*nn + zg*hs[fm][e];
            hs[fm][e] = hn;
            exch[rl*16 + r16] = f2bf(hn);
          }
        __syncthreads();
        {
          unsigned short* dst = h0 + (size_t)ju*HB;        // h0(t) = step u
          int r = tid;
          u32x4 v0 = *(const u32x4*)&exch[r*16];
          u32x4 v1 = *(const u32x4*)&exch[r*16 + 8];
          unsigned short* dp = dst + ((size_t)(bmB + r))*512 + jt*16;
          st16_sc1(dp,     v0);
          st16_sc1(dp + 8, v1);
        }
      }
    } else if (xg == 6) {
      // ---------------- fc1, step t = u-1 ----------------
      if (u >= 1 && u <= 254) {
        const int bmB = (sub >> 3) * 128, bnB = (sub & 7) * 64;
        const unsigned short* h1r = h1 + (size_t)jm2*HB;   // h1(t-1)
        const float* s0p = P.states + (size_t)(u-1)*BATCH*32;
        f32x4 acc[4][2] = {};
        const int arow = bmB + (wv>>1)*64;
        const int bcol = (wv&1)*32;
        #pragma unroll 2
        for (int kt = 0; kt < 19; ++kt) {
          const int k = kt*32 + kg*8;
          bfrag a[4];
          #pragma unroll
          for (int fm = 0; fm < 4; ++fm) {
            int row = arow + fm*16 + r16;
            int rl  = row - bmB;
            if (kt == 0)      a[fm] = cvt8(&s0p[(size_t)row*32 + k]);
            else if (kt <= 2) a[fm] = *(const bfrag*)&sm[47616 + rl*64 + (k - 32)];
            else              a[fm] = *(const bfrag*)&h1r[(size_t)row*512 + (k - 96)];
          }
          bfrag bf0 = *(const bfrag*)&sm[(bcol      + r16)*616 + k];
          bfrag bf1 = *(const bfrag*)&sm[(bcol + 16 + r16)*616 + k];
          #pragma unroll
          for (int fm = 0; fm < 4; ++fm) {
            acc[fm][0] = MFMA(a[fm], bf0, acc[fm][0]);
            acc[fm][1] = MFMA(a[fm], bf1, acc[fm][1]);
          }
        }
        unsigned short* exch = sm + 39424;          // [128][64]
        #pragma unroll
        for (int fm = 0; fm < 4; ++fm)
          #pragma unroll
          for (int fn = 0; fn < 2; ++fn) {
            float bias = fn ? b1 : b0;
            #pragma unroll
            for (int e = 0; e < 4; ++e) {
              int rl = (wv>>1)*64 + fm*16 + kg*4 + e;
              int cl = bcol + fn*16 + r16;
              exch[rl*64 + cl] = f2bf(fmaxf(acc[fm][fn][e] + bias, 0.f));
            }
          }
        __syncthreads();
        {
          unsigned short* dst = d1 + (size_t)jm1*HB;       // dh1(t) = step u-1
          int r = tid >> 1, hc = tid & 1;
          #pragma unroll
          for (int q = 0; q < 4; ++q) {
            u32x4 v = *(const u32x4*)&exch[r*64 + hc*32 + q*8];
            st16_sc1(dst + ((size_t)(bmB + r))*512 + bnB + hc*32 + q*8, v);
          }
        }
        __syncthreads();
      }
    } else {
      // ---------------- fc2, step t = u-2 ----------------
      if (u >= 2 && u <= 255) {
        const int bmB = (sub >> 3) * 128, bnB = (sub & 7) * 64;
        const unsigned short* dr = d1 + (size_t)jm2*HB;    // dh1(t)
        f32x4 acc[4][2] = {};
        const int arow = bmB + (wv>>1)*64;
        const int bcol = (wv&1)*32;
        #pragma unroll 2
        for (int kt = 0; kt < 16; ++kt) {
          const int k = kt*32 + kg*8;
          bfrag a[4];
          #pragma unroll
          for (int fm = 0; fm < 4; ++fm) {
            int row = arow + fm*16 + r16;
            a[fm] = *(const bfrag*)&dr[(size_t)row*512 + k];
          }
          bfrag bf0 = *(const bfrag*)&sm[(bcol      + r16)*520 + k];
          bfrag bf1 = *(const bfrag*)&sm[(bcol + 16 + r16)*520 + k];
          #pragma unroll
          for (int fm = 0; fm < 4; ++fm) {
            acc[fm][0] = MFMA(a[fm], bf0, acc[fm][0]);
            acc[fm][1] = MFMA(a[fm], bf1, acc[fm][1]);
          }
        }
        unsigned short* exch = sm + 66560;          // [128][64]
        #pragma unroll
        for (int fm = 0; fm < 4; ++fm)
          #pragma unroll
          for (int fn = 0; fn < 2; ++fn) {
            float bias = fn ? b1 : b0;
            #pragma unroll
            for (int e = 0; e < 4; ++e) {
              int rl = (wv>>1)*64 + fm*16 + kg*4 + e;
              int cl = bcol + fn*16 + r16;
              exch[rl*64 + cl] = f2bf(fmaxf(acc[fm][fn][e] + bias, 0.f));
            }
          }
        __syncthreads();
        {
          unsigned short* dst = d2 + (size_t)jm2*HB;       // dh2(t) = step u-2
          int r = tid >> 1, hc = tid & 1;
          #pragma unroll
          for (int q = 0; q < 4; ++q) {
            u32x4 v = *(const u32x4*)&exch[r*64 + hc*32 + q*8];
            st16_sc1(dst + ((size_t)(bmB + r))*512 + bnB + hc*32 + q*8, v);
          }
        }
      }
      // ---------------- head, step t = u-3 ----------------
      if (u >= 3) {
        const int t = u - 3;
        const unsigned short* dr = d2 + (size_t)jm3*HB;    // dh2(u-3)
        f32x4 acc = {};
        #pragma unroll 2
        for (int kt = 0; kt < 16; ++kt) {
          const int k = kt*32 + kg*8;
          bfrag a = *(const bfrag*)&dr[(size_t)(sub*16 + r16)*512 + k];
          bfrag b = *(const bfrag*)&sm[33280 + (wv*16 + r16)*520 + k];
          acc = MFMA(a, b, acc);
        }
        __syncthreads();                    // fc2's exch use is done
        float* exch = (float*)(sm + 66560); // [16][66]
        const int c = wv*16 + r16;
        #pragma unroll
        for (int e = 0; e < 4; ++e)
          exch[(kg*4+e)*66 + c] = acc[e] + b2;
        __syncthreads();
        const float* s0p = P.states + (size_t)t*BATCH*32;
        #pragma unroll
        for (int e2 = 0; e2 < 2; ++e2) {
          int idx = tid*2 + e2;
          int r = idx >> 5, i = idx & 31;
          int b = sub*16 + r;
          float mean = exch[r*66 + i], lv = exch[r*66 + 32 + i];
          float av = s0p[(size_t)(BATCH + b)*32 + i] - s0p[(size_t)b*32 + i];
          float d = av - mean;
          float v = 0.5f*(d*d*__expf(-lv) + lv + LOG2PI);
          if (e2) nacc1 += v; else nacc0 += v;
        }
      }
    }

    // -------------------- publish --------------------
    __syncthreads();                      // drains all threads' sc1 stores
    if (tid == 0) ASTORE(&flags[blk*16], (unsigned)(u+1));
  }

  if (xg == 7) {
    #pragma unroll
    for (int e2 = 0; e2 < 2; ++e2) {
      int idx = tid*2 + e2;
      int b = sub*16 + (idx >> 5), i = idx & 31;
      P.out[(size_t)b*32 + i] = e2 ? nacc1 : nacc0;
    }
  }
}

extern "C" void kernel_launch(void* const* d_in, const int* in_sizes, int n_in,
                              void* d_out, int out_size, void* d_ws, size_t ws_size,
                              hipStream_t stream) {
  Params P;
  P.states = (const float*)d_in[0];
  P.zin    = (const float*)d_in[1];
  P.Wih0   = (const float*)d_in[2];
  P.Whh0   = (const float*)d_in[3];
  P.bih0   = (const float*)d_in[4];
  P.bhh0   = (const float*)d_in[5];
  P.Wih1   = (const float*)d_in[6];
  P.Whh1   = (const float*)d_in[7];
  P.bih1   = (const float*)d_in[8];
  P.bhh1   = (const float*)d_in[9];
  P.Wfc1   = (const float*)d_in[10];
  P.bfc1   = (const float*)d_in[11];
  P.Wfc2   = (const float*)d_in[12];
  P.bfc2   = (const float*)d_in[13];
  P.Wmean  = (const float*)d_in[14];
  P.bmean  = (const float*)d_in[15];
  P.Wlv    = (const float*)d_in[16];
  P.blv    = (const float*)d_in[17];
  P.out = (float*)d_out;
  P.act = (unsigned short*)d_ws;

  unsigned* flags = (unsigned*)(P.act + 32*(size_t)HB);   // 256 flags @ 64B

  // zero h0+h1 (all 8 slots each; initial h = 0), flags, out
  hipMemsetAsync(P.act, 0, 16*(size_t)HB*sizeof(unsigned short), stream);
  hipMemsetAsync(flags, 0, 256*16*sizeof(unsigned), stream);
  hipMemsetAsync(d_out, 0, (size_t)out_size*sizeof(float), stream);

  fused<<<dim3(256), dim3(256), 0, stream>>>(P, flags);
}

// Round 12
// 3985.567 us; speedup vs baseline: 1.4605x; 1.0886x over previous
//
#include <hip/hip_runtime.h>
#include <math.h>

#define BATCH 512
#define LOG2PI 1.8378770664093453f
#define HB 262144   // 512*512 shorts

typedef __attribute__((ext_vector_type(8))) short bfrag;   // 8 bf16
typedef __attribute__((ext_vector_type(4))) float f32x4;
typedef __attribute__((ext_vector_type(4))) unsigned int u32x4;

#define MFMA(a,b,c) __builtin_amdgcn_mfma_f32_16x16x32_bf16(a,b,c,0,0,0)
#define ASTORE(p,v) __hip_atomic_store((p),(v),__ATOMIC_RELAXED,__HIP_MEMORY_SCOPE_AGENT)
#define ALOAD(p)    __hip_atomic_load((p),__ATOMIC_RELAXED,__HIP_MEMORY_SCOPE_AGENT)

// 16B device-coherent store (sc1): data lands at L3, visible cross-XCD after
// vmcnt drain (proven rounds 6-11).
__device__ __forceinline__ void st16_sc1(void* p, u32x4 v){
  asm volatile("global_store_dwordx4 %0, %1, off sc1" :: "v"(p), "v"(v) : "memory");
}

__device__ __forceinline__ float sigm(float x){ return 1.0f/(1.0f+__expf(-x)); }
__device__ __forceinline__ unsigned short f2bf(float f){
  unsigned int u = __builtin_bit_cast(unsigned int, f);
  u += 0x7FFFu + ((u>>16)&1u);          // RNE
  return (unsigned short)(u>>16);
}
__device__ __forceinline__ bfrag cvt8(const float* __restrict__ p){
  bfrag v;
  #pragma unroll
  for (int e=0;e<8;++e) v[e] = (short)f2bf(p[e]);
  return v;
}
__device__ __forceinline__ bfrag cvt8d(const float* __restrict__ p1, const float* __restrict__ p0){
  bfrag v;
  #pragma unroll
  for (int e=0;e<8;++e) v[e] = (short)f2bf(p1[e]-p0[e]);
  return v;
}

struct Params {
  const float *states, *zin;
  const float *Wih0, *Whh0, *bih0, *bhh0;
  const float *Wih1, *Whh1, *bih1, *bhh1;
  const float *Wfc1, *bfc1, *Wfc2, *bfc2;
  const float *Wmean, *bmean, *Wlv, *blv;
  unsigned short *act;   // h0[8*HB] | h1[8*HB] | d1[8*HB] | d2[8*HB]
  float *out;
};

// Roles (xg = blk&7, sub = blk>>3), identical to round 11:
//   xg 0-3: gru1  rows xg*128, j-tile=sub.  LDS: W [3][16][1032], exch@49536
//   xg 4-5: gru0  rows (xg-4)*256, j-tile=sub. LDS: W [3][16][584], exch@28032
//   xg 6:   fc1   bm=sub>>3, bn=sub&7. LDS: W [64][616], exch@39424, z@47616
//   xg 7:   fc2+head. LDS: W x2 @0/33280, exch@66560
// Sync: LEADER (sub==0) per xg does the union producer wait + full agent
// acquire fence (L1+L2 inv) ONCE per XCD per phase, publishes xcdf[xg].
// Followers poll xcdf then do an L1-only `buffer_inv` — L2 stays warm and
// shared across the XCD's 32 blocks.
__global__ __launch_bounds__(256, 1) void fused(Params P, unsigned* flags, unsigned* xcdf) {
  __shared__ unsigned short sm[74752];   // 149504 B static LDS
  const int tid  = threadIdx.x;
  const int lane = tid & 63;
  const int wv   = tid >> 6;
  const int r16  = lane & 15, kg = lane >> 4;
  const int blk  = blockIdx.x;
  const int xg   = blk & 7, sub = blk >> 3;

  unsigned short* h0 = P.act;
  unsigned short* h1 = P.act +  8*(size_t)HB;
  unsigned short* d1 = P.act + 16*(size_t)HB;
  unsigned short* d2 = P.act + 24*(size_t)HB;

  // ---------------- startup: stage weights (+z) into LDS (bf16) -----------
  if (xg < 4) {
    const int jt = sub;
    const float* Wsrc[2] = {P.Wih1, P.Whh1};
    #pragma unroll
    for (int m = 0; m < 2; ++m) {
      const float* W = Wsrc[m];
      for (int c = tid; c < 3072; c += 256) {
        int g = c >> 10, rem = c & 1023;
        int r = rem >> 6, k = (rem & 63) << 3;
        *(bfrag*)&sm[(g*16+r)*1032 + m*512 + k] =
          cvt8(&W[((size_t)(g*512 + jt*16 + r))*512 + k]);
      }
    }
  } else if (xg < 6) {
    const int jt = sub;
    for (int c = tid; c < 384; c += 256) {
      int g = c >> 7, rem = c & 127;
      int r = rem >> 3, k = (rem & 7) << 3;
      *(bfrag*)&sm[(g*16+r)*584 + k] =
        cvt8(&P.Wih0[((size_t)(g*512 + jt*16 + r))*64 + k]);
    }
    for (int c = tid; c < 3072; c += 256) {
      int g = c >> 10, rem = c & 1023;
      int r = rem >> 6, k = (rem & 63) << 3;
      *(bfrag*)&sm[(g*16+r)*584 + 64 + k] =
        cvt8(&P.Whh0[((size_t)(g*512 + jt*16 + r))*512 + k]);
    }
  } else if (xg == 6) {
    const int bn = (sub & 7) * 64;
    const int bmB = (sub >> 3) * 128;
    for (int c = tid; c < 4864; c += 256) {
      int n = c / 76, k = (c % 76) << 3;
      *(bfrag*)&sm[n*616 + k] = cvt8(&P.Wfc1[(size_t)(bn + n)*608 + k]);
    }
    for (int c = tid; c < 1024; c += 256) {      // z slice rows bmB..bmB+127
      int r = c >> 3, k = (c & 7) << 3;
      *(bfrag*)&sm[47616 + r*64 + k] = cvt8(&P.zin[(size_t)(bmB + r)*64 + k]);
    }
  } else {
    const int bn = (sub & 7) * 64;
    for (int c = tid; c < 4096; c += 256) {
      int n = c >> 6, k = (c & 63) << 3;
      *(bfrag*)&sm[n*520 + k] = cvt8(&P.Wfc2[(size_t)(bn + n)*512 + k]);
    }
    for (int c = tid; c < 4096; c += 256) {
      int m = c >> 6, k = (c & 63) << 3;
      const float* src = (m < 32) ? &P.Wmean[(size_t)m*512 + k]
                                  : &P.Wlv[(size_t)(m-32)*512 + k];
      *(bfrag*)&sm[33280 + m*520 + k] = cvt8(src);
    }
  }

  // ---------------- hoisted per-thread biases ----------------
  float b0 = 0.f, b1 = 0.f, b2 = 0.f, b3 = 0.f;
  if (xg < 4) {
    int j = sub*16 + r16;
    b0 = P.bih1[j] + P.bhh1[j];
    b1 = P.bih1[j+512] + P.bhh1[j+512];
    b2 = P.bih1[j+1024]; b3 = P.bhh1[j+1024];
  } else if (xg < 6) {
    int j = sub*16 + r16;
    b0 = P.bih0[j] + P.bhh0[j];
    b1 = P.bih0[j+512] + P.bhh0[j+512];
    b2 = P.bih0[j+1024]; b3 = P.bhh0[j+1024];
  } else if (xg == 6) {
    int nn0 = (sub & 7)*64 + (wv&1)*32 + r16;
    b0 = P.bfc1[nn0]; b1 = P.bfc1[nn0+16];
  } else {
    int nn0 = (sub & 7)*64 + (wv&1)*32 + r16;
    b0 = P.bfc2[nn0]; b1 = P.bfc2[nn0+16];
    int c = wv*16 + r16;
    b2 = (c < 32) ? P.bmean[c] : P.blv[c-32];
  }
  float hs[4][4] = {};                  // gru f32 master state (regs)
  float nacc0 = 0.f, nacc1 = 0.f;

  for (int u = 0; u <= 256; ++u) {
    // ---------- sync: leader union-wait + L2 inv; followers L1-only ----------
    if (sub == 0) {
      if (wv == 0) {
        // union producer wait for the whole xg group (superset of every
        // follower's r11 wait set; sub-dependent sets widened to the union)
        int pb1 = -1, pb2 = -1, pb3 = -1;
        const unsigned t1 = (unsigned)u, t2 = (unsigned)(u - 6);
        if (xg >= 4 && xg < 6) {          // gru0: own>=u ; gru1 consumers >=u-6
          if (u >= 1 && lane < 32) pb1 = lane*8 + xg;
          if (u >= 7)              pb2 = (lane>>1)*8 + 2*(xg-4) + (lane&1);
        } else if (xg < 4) {              // gru1: own+gru0 >=u ; fc1 >=u-6
          if (u >= 1) pb1 = (lane < 32) ? lane*8 + xg : (lane-32)*8 + 4 + (xg>>1);
          if (u >= 7 && lane < 8) pb2 = (xg*8 + lane)*8 + 6;
        } else if (xg == 6) {             // fc1: ALL gru1 >=u ; ALL fc2 >=u-6
          if (u >= 1) { pb1 = (lane>>2)*8 + (lane&3); pb3 = pb1 + 128; }
          if (u >= 7 && lane < 32) pb2 = lane*8 + 7;
        } else {                          // fc2/head: ALL fc1 + ALL fc2 >=u
          if (u >= 1) pb1 = (lane < 32) ? lane*8 + 6 : (lane-32)*8 + 7;
        }
        unsigned spin = 0;
        while (true) {
          bool ok = true;
          if (pb1 >= 0) ok &= (ALOAD(&flags[pb1*16]) >= t1);
          if (pb3 >= 0) ok &= (ALOAD(&flags[pb3*16]) >= t1);
          if (pb2 >= 0) ok &= (ALOAD(&flags[pb2*16]) >= t2);
          if (__all(ok)) break;
          if (++spin > (1u<<26)) break;   // safety: never hang the harness
          __builtin_amdgcn_s_sleep(1);
        }
      }
      __syncthreads();
      if (tid < 64) __builtin_amdgcn_fence(__ATOMIC_ACQUIRE, "agent"); // L1+L2 inv
      __syncthreads();
      if (tid == 0) ASTORE(&xcdf[xg*16], (unsigned)(u+1));
    } else {
      if (wv == 0 && lane == 0) {
        unsigned spin = 0;
        while (ALOAD(&xcdf[xg*16]) < (unsigned)(u+1)) {
          if (++spin > (1u<<26)) break;   // safety
          __builtin_amdgcn_s_sleep(1);
        }
      }
      __syncthreads();
      if (tid < 64)
        asm volatile("buffer_inv\n\ts_waitcnt vmcnt(0)" ::: "memory"); // L1-only
      __syncthreads();
    }

    const int ju  = u & 7;              // slot of step u
    const int jm1 = (u+7) & 7;          // step u-1
    const int jm2 = (u+6) & 7;          // step u-2
    const int jm3 = (u+5) & 7;          // step u-3

    if (xg < 4) {
      // ---------------- gru1, step t = u-1 ----------------
      if (u >= 1 && u <= 254) {
        const int jt = sub, bmB = xg * 128;
        const unsigned short* h0r = h0 + (size_t)jm1*HB;   // h0(t)
        const unsigned short* h1r = h1 + (size_t)jm2*HB;   // h1(t-1)
        f32x4 R[2]={}, Z[2]={}, NI[2]={}, NH[2]={};
        const int row0 = bmB + wv*32 + r16;
        #pragma unroll
        for (int half = 0; half < 2; ++half) {
          const unsigned short* asrc = half ? h1r : h0r;
          #pragma unroll 4
          for (int kt = 0; kt < 16; ++kt) {
            const int kk = kt*32 + kg*8;
            const int kl = half*512 + kk;
            bfrag a0 = *(const bfrag*)&asrc[(size_t)row0*512 + kk];
            bfrag a1 = *(const bfrag*)&asrc[(size_t)(row0+16)*512 + kk];
            bfrag bR = *(const bfrag*)&sm[(0*16+r16)*1032 + kl];
            bfrag bZ = *(const bfrag*)&sm[(1*16+r16)*1032 + kl];
            bfrag bN = *(const bfrag*)&sm[(2*16+r16)*1032 + kl];
            R[0]=MFMA(a0,bR,R[0]); R[1]=MFMA(a1,bR,R[1]);
            Z[0]=MFMA(a0,bZ,Z[0]); Z[1]=MFMA(a1,bZ,Z[1]);
            if (!half) { NI[0]=MFMA(a0,bN,NI[0]); NI[1]=MFMA(a1,bN,NI[1]); }
            else       { NH[0]=MFMA(a0,bN,NH[0]); NH[1]=MFMA(a1,bN,NH[1]); }
          }
        }
        unsigned short* exch = sm + 49536;          // [128][16]
        #pragma unroll
        for (int fm = 0; fm < 2; ++fm)
          #pragma unroll
          for (int e = 0; e < 4; ++e) {
            int rl = wv*32 + fm*16 + kg*4 + e;
            float r  = sigm(R[fm][e] + b0);
            float zg = sigm(Z[fm][e] + b1);
            float nn = tanhf(NI[fm][e] + b2 + r*(NH[fm][e] + b3));
            float hn = (1.f - zg)*nn + zg*hs[fm][e];
            hs[fm][e] = hn;
            exch[rl*16 + r16] = f2bf(hn);
          }
        __syncthreads();
        {
          unsigned short* dst = h1 + (size_t)jm1*HB;       // h1(t) = step u-1
          int r = tid >> 1, hc = tid & 1;
          u32x4 v = *(const u32x4*)&exch[r*16 + hc*8];
          st16_sc1(dst + ((size_t)(bmB + r))*512 + jt*16 + hc*8, v);
        }
      }
    } else if (xg < 6) {
      // ---------------- gru0, step t = u ----------------
      if (u <= 253) {
        const int jt = sub, bmB = (xg - 4) * 256;
        const unsigned short* h0r = h0 + (size_t)jm1*HB;   // h0(t-1)
        const float* s0p = P.states + (size_t)u*BATCH*32;
        f32x4 R[4]={}, Z[4]={}, NI[4]={}, NH[4]={};
        #pragma unroll
        for (int ks = 0; ks < 2; ++ks) {             // K=64: s then a
          const int kl = ks*32 + kg*8;
          bfrag a[4];
          #pragma unroll
          for (int fm = 0; fm < 4; ++fm) {
            int row = bmB + wv*64 + fm*16 + r16;
            a[fm] = (ks == 0)
              ? cvt8(&s0p[(size_t)row*32 + kg*8])
              : cvt8d(&s0p[(size_t)(BATCH + row)*32 + kg*8], &s0p[(size_t)row*32 + kg*8]);
          }
          bfrag bR = *(const bfrag*)&sm[(0*16+r16)*584 + kl];
          bfrag bZ = *(const bfrag*)&sm[(1*16+r16)*584 + kl];
          bfrag bN = *(const bfrag*)&sm[(2*16+r16)*584 + kl];
          #pragma unroll
          for (int fm = 0; fm < 4; ++fm) {
            R[fm]=MFMA(a[fm],bR,R[fm]); Z[fm]=MFMA(a[fm],bZ,Z[fm]); NI[fm]=MFMA(a[fm],bN,NI[fm]);
          }
        }
        #pragma unroll 2
        for (int kt = 0; kt < 16; ++kt) {            // K=512: h0
          const int kk = kt*32 + kg*8;
          const int kl = 64 + kk;
          bfrag a[4];
          #pragma unroll
          for (int fm = 0; fm < 4; ++fm) {
            int row = bmB + wv*64 + fm*16 + r16;
            a[fm] = *(const bfrag*)&h0r[(size_t)row*512 + kk];
          }
          bfrag bR = *(const bfrag*)&sm[(0*16+r16)*584 + kl];
          bfrag bZ = *(const bfrag*)&sm[(1*16+r16)*584 + kl];
          bfrag bN = *(const bfrag*)&sm[(2*16+r16)*584 + kl];
          #pragma unroll
          for (int fm = 0; fm < 4; ++fm) {
            R[fm]=MFMA(a[fm],bR,R[fm]); Z[fm]=MFMA(a[fm],bZ,Z[fm]); NH[fm]=MFMA(a[fm],bN,NH[fm]);
          }
        }
        unsigned short* exch = sm + 28032;          // [256][16]
        #pragma unroll
        for (int fm = 0; fm < 4; ++fm)
          #pragma unroll
          for (int e = 0; e < 4; ++e) {
            int rl = wv*64 + fm*16 + kg*4 + e;
            float r  = sigm(R[fm][e] + b0);
            float zg = sigm(Z[fm][e] + b1);
            float nn = tanhf(NI[fm][e] + b2 + r*(NH[fm][e] + b3));
            float hn = (1.f - zg)*nn + zg*hs[fm][e];
            hs[fm][e] = hn;
            exch[rl*16 + r16] = f2bf(hn);
          }
        __syncthreads();
        {
          unsigned short* dst = h0 + (size_t)ju*HB;        // h0(t) = step u
          int r = tid;
          u32x4 v0 = *(const u32x4*)&exch[r*16];
          u32x4 v1 = *(const u32x4*)&exch[r*16 + 8];
          unsigned short* dp = dst + ((size_t)(bmB + r))*512 + jt*16;
          st16_sc1(dp,     v0);
          st16_sc1(dp + 8, v1);
        }
      }
    } else if (xg == 6) {
      // ---------------- fc1, step t = u-1 ----------------
      if (u >= 1 && u <= 254) {
        const int bmB = (sub >> 3) * 128, bnB = (sub & 7) * 64;
        const unsigned short* h1r = h1 + (size_t)jm2*HB;   // h1(t-1)
        const float* s0p = P.states + (size_t)(u-1)*BATCH*32;
        f32x4 acc[4][2] = {};
        const int arow = bmB + (wv>>1)*64;
        const int bcol = (wv&1)*32;
        #pragma unroll 2
        for (int kt = 0; kt < 19; ++kt) {
          const int k = kt*32 + kg*8;
          bfrag a[4];
          #pragma unroll
          for (int fm = 0; fm < 4; ++fm) {
            int row = arow + fm*16 + r16;
            int rl  = row - bmB;
            if (kt == 0)      a[fm] = cvt8(&s0p[(size_t)row*32 + k]);
            else if (kt <= 2) a[fm] = *(const bfrag*)&sm[47616 + rl*64 + (k - 32)];
            else              a[fm] = *(const bfrag*)&h1r[(size_t)row*512 + (k - 96)];
          }
          bfrag bf0 = *(const bfrag*)&sm[(bcol      + r16)*616 + k];
          bfrag bf1 = *(const bfrag*)&sm[(bcol + 16 + r16)*616 + k];
          #pragma unroll
          for (int fm = 0; fm < 4; ++fm) {
            acc[fm][0] = MFMA(a[fm], bf0, acc[fm][0]);
            acc[fm][1] = MFMA(a[fm], bf1, acc[fm][1]);
          }
        }
        unsigned short* exch = sm + 39424;          // [128][64]
        #pragma unroll
        for (int fm = 0; fm < 4; ++fm)
          #pragma unroll
          for (int fn = 0; fn < 2; ++fn) {
            float bias = fn ? b1 : b0;
            #pragma unroll
            for (int e = 0; e < 4; ++e) {
              int rl = (wv>>1)*64 + fm*16 + kg*4 + e;
              int cl = bcol + fn*16 + r16;
              exch[rl*64 + cl] = f2bf(fmaxf(acc[fm][fn][e] + bias, 0.f));
            }
          }
        __syncthreads();
        {
          unsigned short* dst = d1 + (size_t)jm1*HB;       // dh1(t) = step u-1
          int r = tid >> 1, hc = tid & 1;
          #pragma unroll
          for (int q = 0; q < 4; ++q) {
            u32x4 v = *(const u32x4*)&exch[r*64 + hc*32 + q*8];
            st16_sc1(dst + ((size_t)(bmB + r))*512 + bnB + hc*32 + q*8, v);
          }
        }
        __syncthreads();
      }
    } else {
      // ---------------- fc2, step t = u-2 ----------------
      if (u >= 2 && u <= 255) {
        const int bmB = (sub >> 3) * 128, bnB = (sub & 7) * 64;
        const unsigned short* dr = d1 + (size_t)jm2*HB;    // dh1(t)
        f32x4 acc[4][2] = {};
        const int arow = bmB + (wv>>1)*64;
        const int bcol = (wv&1)*32;
        #pragma unroll 2
        for (int kt = 0; kt < 16; ++kt) {
          const int k = kt*32 + kg*8;
          bfrag a[4];
          #pragma unroll
          for (int fm = 0; fm < 4; ++fm) {
            int row = arow + fm*16 + r16;
            a[fm] = *(const bfrag*)&dr[(size_t)row*512 + k];
          }
          bfrag bf0 = *(const bfrag*)&sm[(bcol      + r16)*520 + k];
          bfrag bf1 = *(const bfrag*)&sm[(bcol + 16 + r16)*520 + k];
          #pragma unroll
          for (int fm = 0; fm < 4; ++fm) {
            acc[fm][0] = MFMA(a[fm], bf0, acc[fm][0]);
            acc[fm][1] = MFMA(a[fm], bf1, acc[fm][1]);
          }
        }
        unsigned short* exch = sm + 66560;          // [128][64]
        #pragma unroll
        for (int fm = 0; fm < 4; ++fm)
          #pragma unroll
          for (int fn = 0; fn < 2; ++fn) {
            float bias = fn ? b1 : b0;
            #pragma unroll
            for (int e = 0; e < 4; ++e) {
              int rl = (wv>>1)*64 + fm*16 + kg*4 + e;
              int cl = bcol + fn*16 + r16;
              exch[rl*64 + cl] = f2bf(fmaxf(acc[fm][fn][e] + bias, 0.f));
            }
          }
        __syncthreads();
        {
          unsigned short* dst = d2 + (size_t)jm2*HB;       // dh2(t) = step u-2
          int r = tid >> 1, hc = tid & 1;
          #pragma unroll
          for (int q = 0; q < 4; ++q) {
            u32x4 v = *(const u32x4*)&exch[r*64 + hc*32 + q*8];
            st16_sc1(dst + ((size_t)(bmB + r))*512 + bnB + hc*32 + q*8, v);
          }
        }
      }
      // ---------------- head, step t = u-3 ----------------
      if (u >= 3) {
        const int t = u - 3;
        const unsigned short* dr = d2 + (size_t)jm3*HB;    // dh2(u-3)
        f32x4 acc = {};
        #pragma unroll 2
        for (int kt = 0; kt < 16; ++kt) {
          const int k = kt*32 + kg*8;
          bfrag a = *(const bfrag*)&dr[(size_t)(sub*16 + r16)*512 + k];
          bfrag b = *(const bfrag*)&sm[33280 + (wv*16 + r16)*520 + k];
          acc = MFMA(a, b, acc);
        }
        __syncthreads();                    // fc2's exch use is done
        float* exch = (float*)(sm + 66560); // [16][66]
        const int c = wv*16 + r16;
        #pragma unroll
        for (int e = 0; e < 4; ++e)
          exch[(kg*4+e)*66 + c] = acc[e] + b2;
        __syncthreads();
        const float* s0p = P.states + (size_t)t*BATCH*32;
        #pragma unroll
        for (int e2 = 0; e2 < 2; ++e2) {
          int idx = tid*2 + e2;
          int r = idx >> 5, i = idx & 31;
          int b = sub*16 + r;
          float mean = exch[r*66 + i], lv = exch[r*66 + 32 + i];
          float av = s0p[(size_t)(BATCH + b)*32 + i] - s0p[(size_t)b*32 + i];
          float d = av - mean;
          float v = 0.5f*(d*d*__expf(-lv) + lv + LOG2PI);
          if (e2) nacc1 += v; else nacc0 += v;
        }
      }
    }

    // -------------------- publish --------------------
    __syncthreads();                      // drains all threads' sc1 stores
    if (tid == 0) ASTORE(&flags[blk*16], (unsigned)(u+1));
  }

  if (xg == 7) {
    #pragma unroll
    for (int e2 = 0; e2 < 2; ++e2) {
      int idx = tid*2 + e2;
      int b = sub*16 + (idx >> 5), i = idx & 31;
      P.out[(size_t)b*32 + i] = e2 ? nacc1 : nacc0;
    }
  }
}

extern "C" void kernel_launch(void* const* d_in, const int* in_sizes, int n_in,
                              void* d_out, int out_size, void* d_ws, size_t ws_size,
                              hipStream_t stream) {
  Params P;
  P.states = (const float*)d_in[0];
  P.zin    = (const float*)d_in[1];
  P.Wih0   = (const float*)d_in[2];
  P.Whh0   = (const float*)d_in[3];
  P.bih0   = (const float*)d_in[4];
  P.bhh0   = (const float*)d_in[5];
  P.Wih1   = (const float*)d_in[6];
  P.Whh1   = (const float*)d_in[7];
  P.bih1   = (const float*)d_in[8];
  P.bhh1   = (const float*)d_in[9];
  P.Wfc1   = (const float*)d_in[10];
  P.bfc1   = (const float*)d_in[11];
  P.Wfc2   = (const float*)d_in[12];
  P.bfc2   = (const float*)d_in[13];
  P.Wmean  = (const float*)d_in[14];
  P.bmean  = (const float*)d_in[15];
  P.Wlv    = (const float*)d_in[16];
  P.blv    = (const float*)d_in[17];
  P.out = (float*)d_out;
  P.act = (unsigned short*)d_ws;

  unsigned* flags = (unsigned*)(P.act + 32*(size_t)HB);   // 256 flags @ 64B
  unsigned* xcdf  = flags + 256*16;                       // 8 flags @ 64B

  // zero h0+h1 (all 8 slots each; initial h = 0), flags+xcdf, out
  hipMemsetAsync(P.act, 0, 16*(size_t)HB*sizeof(unsigned short), stream);
  hipMemsetAsync(flags, 0, (256*16 + 8*16)*sizeof(unsigned), stream);
  hipMemsetAsync(d_out, 0, (size_t)out_size*sizeof(float), stream);

  fused<<<dim3(256), dim3(256), 0, stream>>>(P, flags, xcdf);
}